// Round 2
// baseline (150.610 us; speedup 1.0000x reference)
//
#include <hip/hip_runtime.h>
#include <hip/hip_bf16.h>

#define NB 8
#define ND 768
#define NCH 3
#define NMIX 5
#define NH 10
#define NS 10

#define HALF_PI2SQ 19.739208802178716f           // 0.5 * (2*pi)^2
#define EXP2_SCALE 28.47780760903922f            // HALF_PI2SQ * log2(e)
#define ZITTERF 1e-4f

// sin/cos of 2*pi*t via hardware v_sin/v_cos (input in revolutions), shared fract
__device__ __forceinline__ void sincos2pi(float t, float& s, float& c) {
    const float f = __builtin_amdgcn_fractf(t);
    s = __builtin_amdgcn_sinf(f);
    c = __builtin_amdgcn_cosf(f);
}

// ---------------------------------------------------------------------------
// Kernel A: feature[b,i,c,m] = sum_j K[b,m,i,j,c]*yc[b,j,c]; writes tif[b,i,c,0..5]
// One wave per (b,c,4-row i-tile); lanes stride j; trig factorized:
// cos(2pi*mu*(xi-xj)) = ci*cj + si*sj with per-point trig held in registers.
// ---------------------------------------------------------------------------
__global__ void __launch_bounds__(256) feature_kernel(
        const float* __restrict__ xc, const float* __restrict__ yc,
        const float* __restrict__ mu, const float* __restrict__ istd,
        float* __restrict__ tif) {
    const int wid  = (blockIdx.x << 2) + (threadIdx.x >> 6);   // 4608 waves
    const int lane = threadIdx.x & 63;
    const int b   = wid / (NCH * (ND / 4));
    const int rem = wid % (NCH * (ND / 4));
    const int c   = rem / (ND / 4);
    const int i0  = (rem % (ND / 4)) * 4;

    float cmu[NMIX], ce2[NMIX];
#pragma unroll
    for (int m = 0; m < NMIX; ++m) {
        const float is = istd[m];
        cmu[m] = mu[m];
        ce2[m] = -EXP2_SCALE * is * is;
    }

    float xi[4], ci[4][NMIX], si[4][NMIX];
#pragma unroll
    for (int t = 0; t < 4; ++t) {
        xi[t] = xc[(b * ND + i0 + t) * NCH + c];
#pragma unroll
        for (int m = 0; m < NMIX; ++m)
            sincos2pi(cmu[m] * xi[t], si[t][m], ci[t][m]);
    }

    float acc[4][NMIX];
#pragma unroll
    for (int t = 0; t < 4; ++t)
#pragma unroll
        for (int m = 0; m < NMIX; ++m) acc[t][m] = 0.f;

    for (int j = lane; j < ND; j += 64) {
        const float xj = xc[(b * ND + j) * NCH + c];
        const float yj = yc[(b * ND + j) * NCH + c];
        float cj[NMIX], sj[NMIX];
#pragma unroll
        for (int m = 0; m < NMIX; ++m)
            sincos2pi(cmu[m] * xj, sj[m], cj[m]);
#pragma unroll
        for (int t = 0; t < 4; ++t) {
            const float dx  = xi[t] - xj;
            const float dx2 = dx * dx;
#pragma unroll
            for (int m = 0; m < NMIX; ++m) {
                const float e  = __builtin_amdgcn_exp2f(ce2[m] * dx2);
                const float cv = fmaf(ci[t][m], cj[m], si[t][m] * sj[m]);
                acc[t][m] = fmaf(e * cv, yj, acc[t][m]);
            }
        }
    }

#pragma unroll
    for (int t = 0; t < 4; ++t)
#pragma unroll
        for (int m = 0; m < NMIX; ++m)
            for (int off = 32; off; off >>= 1)
                acc[t][m] += __shfl_down(acc[t][m], off);

    if (lane == 0) {
#pragma unroll
        for (int t = 0; t < 4; ++t) {
            const float yi = yc[(b * ND + i0 + t) * NCH + c];
            float* tp = tif + ((b * ND + i0 + t) * NCH + c) * (NMIX + 1);
#pragma unroll
            for (int m = 0; m < NMIX; ++m) tp[m] = acc[t][m] + ZITTERF * yi;
            tp[NMIX] = yi;
        }
    }
}

// ---------------------------------------------------------------------------
// Kernel B: per-batch MLP + Gumbel-softmax -> w[b, c*5+m]. One block per batch.
// All weights prefetched to LDS at block start (hidden behind the tif loop).
// ---------------------------------------------------------------------------
__global__ void __launch_bounds__(256) mlp_gumbel_kernel(
        const float* __restrict__ tif,
        const float* __restrict__ W1, const float* __restrict__ b1,
        const float* __restrict__ W2, const float* __restrict__ b2,
        const float* __restrict__ W3, const float* __restrict__ b3,
        const float* __restrict__ W4, const float* __restrict__ b4,
        const float* __restrict__ W5, const float* __restrict__ b5,
        const float* __restrict__ unif,
        float* __restrict__ wout) {
    const int b   = blockIdx.x;
    const int tid = threadIdx.x;

    __shared__ float sW1[NH * 6], sW2[NH * NCH * NH], sW3[NH * NH], sW4[NH * NH],
                     sW5[NCH * NMIX * NH];
    __shared__ float sb1[NH], sb2[NH], sb3[NH], sb4[NH], sb5[NCH * NMIX];
    __shared__ float red[4][NCH * NH];
    __shared__ float hvec[NCH * NH], h2[NH], h3[NH], h4[NH], ll[NCH * NMIX], wacc[NCH * NMIX];

    // prefetch all weights/biases (issued before the compute loop; one sync)
    if (tid < NH * 6) sW1[tid] = W1[tid];
    for (int t = tid; t < NH * NCH * NH; t += 256) sW2[t] = W2[t];
    if (tid < NH * NH) sW3[tid] = W3[tid];
    if (tid < NH * NH) sW4[tid] = W4[tid];
    if (tid < NCH * NMIX * NH) sW5[tid] = W5[tid];
    if (tid < NH) { sb1[tid] = b1[tid]; sb2[tid] = b2[tid]; sb3[tid] = b3[tid]; sb4[tid] = b4[tid]; }
    if (tid < NCH * NMIX) { sb5[tid] = b5[tid]; wacc[tid] = 0.f; }
    __syncthreads();

    float part[NCH * NH];
#pragma unroll
    for (int t = 0; t < NCH * NH; ++t) part[t] = 0.f;

    for (int ii = tid; ii < ND; ii += 256) {
        for (int c = 0; c < NCH; ++c) {
            const float* tp = tif + ((b * ND + ii) * NCH + c) * (NMIX + 1);
            float f[6];
#pragma unroll
            for (int m = 0; m < 6; ++m) f[m] = tp[m];
#pragma unroll
            for (int k = 0; k < NH; ++k) {
                float a = sb1[k];
#pragma unroll
                for (int m = 0; m < 6; ++m) a += f[m] * sW1[k * 6 + m];
                part[c * NH + k] += fmaxf(a, 0.f);
            }
        }
    }

#pragma unroll
    for (int t = 0; t < NCH * NH; ++t)
        for (int off = 32; off; off >>= 1)
            part[t] += __shfl_down(part[t], off);

    const int lane = tid & 63, wv = tid >> 6;
    if (lane == 0)
        for (int t = 0; t < NCH * NH; ++t) red[wv][t] = part[t];
    __syncthreads();

    if (tid < NCH * NH)
        hvec[tid] = (red[0][tid] + red[1][tid] + red[2][tid] + red[3][tid]) * (1.f / (float)ND);
    __syncthreads();

    if (tid < NH) {
        float a = sb2[tid];
#pragma unroll
        for (int j = 0; j < NCH * NH; ++j) a += sW2[tid * (NCH * NH) + j] * hvec[j];
        h2[tid] = fmaxf(a, 0.f);
    }
    __syncthreads();
    if (tid < NH) {
        float a = sb3[tid];
#pragma unroll
        for (int j = 0; j < NH; ++j) a += sW3[tid * NH + j] * h2[j];
        h3[tid] = fmaxf(a, 0.f);
    }
    __syncthreads();
    if (tid < NH) {
        float a = sb4[tid];
#pragma unroll
        for (int j = 0; j < NH; ++j) a += sW4[tid * NH + j] * h3[j];
        h4[tid] = fmaxf(a, 0.f);
    }
    __syncthreads();
    if (tid < NCH * NMIX) {
        float a = sb5[tid];
#pragma unroll
        for (int j = 0; j < NH; ++j) a += sW5[tid * NH + j] * h4[j];
        ll[tid] = a;
    }
    __syncthreads();

    if (tid < NS * NCH) {
        const int s = tid / NCH, c = tid % NCH;
        float z[NMIX], zmax = -1e30f;
#pragma unroll
        for (int m = 0; m < NMIX; ++m) {
            const float u = unif[((b * NS + s) * NCH + c) * NMIX + m];
            const float g = -__logf(-__logf(u + 1e-20f));
            z[m] = (g + ll[c * NMIX + m]) * 10.0f;   // / TEMP(=0.1)
            zmax = fmaxf(zmax, z[m]);
        }
        float e[NMIX], se = 0.f;
#pragma unroll
        for (int m = 0; m < NMIX; ++m) { e[m] = __expf(z[m] - zmax); se += e[m]; }
        const float inv = 0.1f / se;  // 1/sum * 1/ns
#pragma unroll
        for (int m = 0; m < NMIX; ++m)
            atomicAdd(&wacc[c * NMIX + m], e[m] * inv);
    }
    __syncthreads();
    if (tid < NCH * NMIX) wout[b * (NCH * NMIX) + tid] = wacc[tid];
}

// ---------------------------------------------------------------------------
// Kernel C: weighted[b,i,j,c] = sum_m w[b,c,m]*K[b,m,i,j,c] (+diag).
// Block = (b, 4-row i-tile, 256-col j-chunk). i-trig staged in LDS (float2,
// broadcast reads); j-trig per-thread in registers; 1 exp per (i,j,c,m).
// ---------------------------------------------------------------------------
__global__ void __launch_bounds__(256) weighted_kernel(
        const float* __restrict__ xc, const float* __restrict__ wmix,
        const float* __restrict__ mu, const float* __restrict__ istd,
        const float* __restrict__ likerr,
        float* __restrict__ out) {
    const int b   = blockIdx.x / ((ND / 4) * (ND / 256));      // 576 blocks per b
    const int rem = blockIdx.x % ((ND / 4) * (ND / 256));
    const int i0  = (rem / (ND / 256)) * 4;
    const int j   = (rem % (ND / 256)) * 256 + threadIdx.x;
    const int tid = threadIdx.x;

    __shared__ float2 strig[4][NCH][NMIX];   // (cos, sin) of 2pi*mu*xi

    if (tid < 4 * NCH * NMIX) {
        const int it = tid / (NCH * NMIX);
        const int r  = tid % (NCH * NMIX);
        const int cc = r / NMIX, m = r % NMIX;
        const float x = xc[(b * ND + i0 + it) * NCH + cc];
        float s, co;
        sincos2pi(mu[m] * x, s, co);
        strig[it][cc][m] = make_float2(co, s);
    }
    __syncthreads();

    // uniform (scalar) constants
    float cmu[NMIX], ce2[NMIX], w[NCH * NMIX], diag[NCH];
#pragma unroll
    for (int m = 0; m < NMIX; ++m) {
        const float is = istd[m];
        cmu[m] = mu[m];
        ce2[m] = -EXP2_SCALE * is * is;
    }
#pragma unroll
    for (int t = 0; t < NCH * NMIX; ++t) w[t] = wmix[b * (NCH * NMIX) + t];
#pragma unroll
    for (int c = 0; c < NCH; ++c) {
        const float lk = fminf(fmaxf(likerr[c], 0.1f), 1.0f);
        diag[c] = ZITTERF + lk * lk;
    }

    // per-thread j data + trig
    float xj[NCH], cj[NCH][NMIX], sj[NCH][NMIX];
#pragma unroll
    for (int c = 0; c < NCH; ++c) {
        xj[c] = xc[(b * ND + j) * NCH + c];
#pragma unroll
        for (int m = 0; m < NMIX; ++m)
            sincos2pi(cmu[m] * xj[c], sj[c][m], cj[c][m]);
    }

#pragma unroll
    for (int it = 0; it < 4; ++it) {
        const int i = i0 + it;
        float res[NCH];
#pragma unroll
        for (int c = 0; c < NCH; ++c) {
            const float xi  = xc[(b * ND + i) * NCH + c];   // uniform -> scalar load
            const float dx  = xi - xj[c];
            const float dx2 = dx * dx;
            float a = 0.f;
#pragma unroll
            for (int m = 0; m < NMIX; ++m) {
                const float2 t2 = strig[it][c][m];
                const float e   = __builtin_amdgcn_exp2f(ce2[m] * dx2);
                const float cv  = fmaf(t2.x, cj[c][m], t2.y * sj[c][m]);
                a = fmaf(w[c * NMIX + m], e * cv, a);
            }
            if (i == j) a += diag[c];
            res[c] = a;
        }
        float* op = out + (size_t)((b * ND + i) * ND + j) * NCH;
        op[0] = res[0];
        op[1] = res[1];
        op[2] = res[2];
    }
}

extern "C" void kernel_launch(void* const* d_in, const int* in_sizes, int n_in,
                              void* d_out, int out_size, void* d_ws, size_t ws_size,
                              hipStream_t stream) {
    const float* xc     = (const float*)d_in[0];
    const float* yc     = (const float*)d_in[1];
    const float* mu     = (const float*)d_in[2];
    const float* istd   = (const float*)d_in[3];
    const float* likerr = (const float*)d_in[4];
    const float* unif   = (const float*)d_in[5];
    const float* W1 = (const float*)d_in[6];  const float* b1 = (const float*)d_in[7];
    const float* W2 = (const float*)d_in[8];  const float* b2 = (const float*)d_in[9];
    const float* W3 = (const float*)d_in[10]; const float* b3 = (const float*)d_in[11];
    const float* W4 = (const float*)d_in[12]; const float* b4 = (const float*)d_in[13];
    const float* W5 = (const float*)d_in[14]; const float* b5 = (const float*)d_in[15];

    float* out  = (float*)d_out;
    float* tif  = (float*)d_ws;                       // NB*ND*NCH*6 floats
    float* wmix = tif + NB * ND * NCH * (NMIX + 1);   // NB*15 floats

    // A: one wave per (b,c,i-tile of 4) -> 8*3*192 = 4608 waves = 1152 blocks
    feature_kernel<<<(NB * NCH * (ND / 4)) / 4, 256, 0, stream>>>(xc, yc, mu, istd, tif);

    // B: one block per batch
    mlp_gumbel_kernel<<<NB, 256, 0, stream>>>(tif, W1, b1, W2, b2, W3, b3, W4, b4,
                                              W5, b5, unif, wmix);

    // C: block = (b, i-tile of 4, j-chunk of 256) -> 8*192*3 = 4608 blocks
    weighted_kernel<<<NB * (ND / 4) * (ND / 256), 256, 0, stream>>>(xc, wmix, mu, istd,
                                                                    likerr, out);
}